// Round 15
// baseline (929.664 us; speedup 1.0000x reference)
//
#include <hip/hip_runtime.h>
#include <stdint.h>

typedef unsigned short u16;
typedef unsigned int   u32;
typedef unsigned char  u8;

using bf16x8 = __attribute__((ext_vector_type(8))) short;
using f32x4  = __attribute__((ext_vector_type(4))) float;

#define DEVF static __device__ __forceinline__

DEVF u16 f2bf(float f){
  u32 u = __builtin_bit_cast(u32, f);
  u32 r = u + 0x7FFFu + ((u >> 16) & 1u);
  return (u16)(r >> 16);
}
DEVF float bf2f(u16 h){
  u32 u = ((u32)h) << 16;
  return __builtin_bit_cast(float, u);
}

DEVF void gload_lds16(const u16* g, u16* s){
  __builtin_amdgcn_global_load_lds(
      (const __attribute__((address_space(1))) u32*)g,
      (__attribute__((address_space(3))) u32*)(u32)(uintptr_t)s,
      16, 0, 0);
}

// ---------------- conversion / utility kernels ----------------

__global__ __launch_bounds__(256) void k_f32_to_bf16(const float* __restrict__ in,
                                                     u16* __restrict__ out, long n){
  long i = (long)blockIdx.x * blockDim.x + threadIdx.x;
  long stride = (long)gridDim.x * blockDim.x;
  for (long j = i * 8; j < n; j += stride * 8){
    float4 a = *(const float4*)(in + j);
    float4 b = *(const float4*)(in + j + 4);
    bf16x8 v;
    v[0]=(short)f2bf(a.x); v[1]=(short)f2bf(a.y); v[2]=(short)f2bf(a.z); v[3]=(short)f2bf(a.w);
    v[4]=(short)f2bf(b.x); v[5]=(short)f2bf(b.y); v[6]=(short)f2bf(b.z); v[7]=(short)f2bf(b.w);
    *(bf16x8*)(out + j) = v;
  }
}

// edge_f[e] (f32 row) -> Ebf[pos[e]] (bf16 row): permuted conversion (dst-order)
__global__ __launch_bounds__(256)
void k_conv_perm(const float* __restrict__ in, const int* __restrict__ pos,
                 u16* __restrict__ out, int E){
  int e = blockIdx.x * 4 + (threadIdx.x >> 6);
  int l = threadIdx.x & 63;
  if (e >= E) return;
  const float* r = in + (size_t)e * 512 + l * 8;
  float4 a = *(const float4*)r, b = *(const float4*)(r + 4);
  bf16x8 v;
  v[0]=(short)f2bf(a.x); v[1]=(short)f2bf(a.y); v[2]=(short)f2bf(a.z); v[3]=(short)f2bf(a.w);
  v[4]=(short)f2bf(b.x); v[5]=(short)f2bf(b.y); v[6]=(short)f2bf(b.z); v[7]=(short)f2bf(b.w);
  *(bf16x8*)(out + (size_t)pos[e] * 512 + l * 8) = v;
}

__global__ __launch_bounds__(256) void k_zero_i32(int* __restrict__ p, int n){
  int i = blockIdx.x * 256 + threadIdx.x;
  if (i < n) p[i] = 0;
}

// W rows [k0, k0+K) of a [*, 512] f32 matrix -> Wt[N=512][K] bf16 (transposed)
__global__ __launch_bounds__(256) void k_transpose_w_off(const float* __restrict__ W,
                                                         u16* __restrict__ Wt,
                                                         int K, int N, int k0){
  int idx = blockIdx.x * 256 + threadIdx.x;
  if (idx < K * N){
    int k = idx / N, n = idx - k * N;
    Wt[(size_t)n * K + k] = f2bf(W[(size_t)(k + k0) * N + n]);
  }
}

// ---------------- counting sort (dst only) ----------------

__global__ __launch_bounds__(256)
void k_hist(const int* __restrict__ key, int* __restrict__ cnt, int E){
  int e = blockIdx.x * 256 + threadIdx.x;
  if (e < E) atomicAdd(&cnt[key[e]], 1);
}

__global__ __launch_bounds__(1024)
void k_scan(const int* __restrict__ cnt, int* __restrict__ offs, int n){
  __shared__ int part[1024];
  int t = threadIdx.x;
  const int PER = (n + 1023) / 1024;
  int base = t * PER;
  int s = 0;
  for (int i = 0; i < PER; ++i){ int idx = base + i; if (idx < n) s += cnt[idx]; }
  part[t] = s;
  __syncthreads();
  for (int o = 1; o < 1024; o <<= 1){
    int v = (t >= o) ? part[t - o] : 0;
    __syncthreads();
    part[t] += v;
    __syncthreads();
  }
  int run = (t == 0) ? 0 : part[t - 1];
  for (int i = 0; i < PER; ++i){
    int idx = base + i;
    if (idx < n){ offs[idx] = run; run += cnt[idx]; }
  }
  if (t == 1023) offs[n] = part[1023];
}

// scatter + inverse permutation + sorted index maps, fused
__global__ __launch_bounds__(256)
void k_scatter_pos(const int* __restrict__ key, const int* __restrict__ srcIn,
                   const int* __restrict__ offs, int* __restrict__ cur,
                   int* __restrict__ pos, int* __restrict__ srcD,
                   int* __restrict__ dstD, int E){
  int e = blockIdx.x * 256 + threadIdx.x;
  if (e < E){
    int d = key[e];
    int p = offs[d] + atomicAdd(&cur[d], 1);
    pos[e] = p;
    srcD[p] = srcIn[e];
    dstD[p] = d;
  }
}

// ====== GEMM 256x256, BK=64, 8 waves, HALF-TILE counted-vmcnt pipeline =========
// m201-faithful T4: staging in 8 half-tile rounds per K-tile (A/B x kk-half x
// row-half); LDS [2buf][2half][256][32]. Waits are vmcnt(4)+barrier at P1 and
// P3 ONLY — 4 loads stay in flight across every barrier (never drain to 0),
// each load gets >=2 phases of latency cover. P2/P4 re-read barrier-certified
// halves (no sync). Per-phase lgkmcnt(0)+sched_barrier (rule #18) + setprio(T5).
// T2 swizzle for 32-col halves: read chunk = kl ^ ((lane16>>1)&3); source
// pre-swizzle chunk = (l&3)^((l>>3)&3) — involution, worst-case 2-way (free).
// T1 = r8-verified chunked XCD swizzle. r13 lesson: no min-waves launch_bounds.
// MODE 0: A[M][K]. MODE 1 (edge, K=1024): k<512 -> A[r], else G1[srcI[r]].
// EPI 0: silu(v+bias)->bf16. 1: raw bf16. 2: raw f32. 3: silu(v+bias+Pm[dstI[r]])->bf16.

#define LDA4(BUF, MH, KK, AF) \
  _Pragma("unroll") for (int m_ = 0; m_ < 4; ++m_) \
    AF[m_] = *(const bf16x8*)&lA[BUF][KK][(wm * 128 + (MH) * 64 + m_ * 16 + lane16) * 32 + \
                                          (kl ^ ((lane16 >> 1) & 3)) * 8];

#define LDB4(BUF, KK, BFR) \
  _Pragma("unroll") for (int n_ = 0; n_ < 4; ++n_) \
    BFR[n_] = *(const bf16x8*)&lB[BUF][KK][(wn * 64 + n_ * 16 + lane16) * 32 + \
                                           (kl ^ ((lane16 >> 1) & 3)) * 8];

#define PHASE_MFMA(MH, AF, BFR) \
  __builtin_amdgcn_s_setprio(1); \
  _Pragma("unroll") for (int m_ = 0; m_ < 4; ++m_) \
    _Pragma("unroll") for (int n_ = 0; n_ < 4; ++n_) \
      acc[(MH) * 4 + m_][n_] = __builtin_amdgcn_mfma_f32_16x16x32_bf16( \
          AF[m_], BFR[n_], acc[(MH) * 4 + m_][n_], 0, 0, 0); \
  __builtin_amdgcn_s_setprio(0);

// round (HH=kk-half, PP=row-half): wave writes rows [PP*128+w*16, +16), 32 cols
#define STAGE_A(BUF, KT_, HH, PP) do{ \
    const int k0_ = (KT_) * 64 + (HH) * 32; \
    const u16* ga_; \
    if (MODE == 0){ ga_ = A + (size_t)srows[PP] * K + k0_ + kchunk; } \
    else { \
      int seg_ = k0_ >> 9, klo_ = k0_ & 511; \
      const u16* b_ = (seg_ == 0) ? A  + (size_t)srows[PP] * 512 \
                                  : G1 + (size_t)sidx1[PP] * 512; \
      ga_ = b_ + klo_ + kchunk; \
    } \
    gload_lds16(ga_, &lA[BUF][HH][((PP) * 128 + w * 16) * 32]); \
  }while(0)

#define STAGE_B(BUF, KT_, HH, PP) \
  gload_lds16(bptr[PP] + (KT_) * 64 + (HH) * 32 + kchunk, \
              &lB[BUF][HH][((PP) * 128 + w * 16) * 32])

#define WAITBAR(N) do{ \
    asm volatile("s_waitcnt vmcnt(" #N ")" ::: "memory"); \
    __builtin_amdgcn_s_barrier(); \
    __builtin_amdgcn_sched_barrier(0); \
  }while(0)

#define LGK0 do{ \
    asm volatile("s_waitcnt lgkmcnt(0)" ::: "memory"); \
    __builtin_amdgcn_sched_barrier(0); \
  }while(0)

template<int MODE, int EPI>
__global__ __launch_bounds__(512)
void k_gemm256(const u16* __restrict__ A, const u16* __restrict__ G1, const u16* __restrict__ G2,
               const int* __restrict__ srcI, const int* __restrict__ dstI,
               const u16* __restrict__ Bt, const float* __restrict__ bias,
               void* __restrict__ out, int M, int K)
{
  __shared__ __align__(16) u16 lA[2][2][256 * 32];
  __shared__ __align__(16) u16 lB[2][2][256 * 32];

  const int tid = threadIdx.x;
  const int w = tid >> 6, l = tid & 63;

  // T1 (r8-verified)
  const int nwg = gridDim.x * gridDim.y;
  const int wgf = blockIdx.y * gridDim.x + blockIdx.x;
  const int lg  = (wgf & 7) * (nwg >> 3) + (wgf >> 3);
  const int col0 = (lg % gridDim.x) * 256;
  const int row0 = (lg / gridDim.x) * 256;

  // staging rows: round row-half PP covers rows [PP*128 + w*16, +16);
  // lane l -> row +(l>>2), physical 16B chunk (l&3)
  int srows[2], sidx1[2];
  const u16* bptr[2];
  #pragma unroll
  for (int it = 0; it < 2; ++it){
    int r = row0 + it * 128 + w * 16 + (l >> 2);
    if (r >= M) r = M - 1;
    srows[it] = r;
    if (MODE == 1){ sidx1[it] = srcI[r]; }
    int n = col0 + it * 128 + w * 16 + (l >> 2);
    bptr[it] = Bt + (size_t)n * K;
  }
  // T2 inverse-swizzled source chunk: physical (l&3) of row (l>>2) holds
  // logical (l&3) ^ ((row>>1)&3) = (l&3) ^ ((l>>3)&3)
  const int kchunk = ((l & 3) ^ ((l >> 3) & 3)) * 8;

  f32x4 acc[8][4];
  #pragma unroll
  for (int m = 0; m < 8; ++m)
    #pragma unroll
    for (int n = 0; n < 4; ++n)
      acc[m][n] = (f32x4){0.f, 0.f, 0.f, 0.f};

  const int wm = w >> 2, wn = w & 3;       // 2 x 4 wave grid
  const int lane16 = l & 15, kl = l >> 4;  // kl = 8-elem K-chunk within 32-col half

  const int KT = K >> 6;

  // prologue: tile 0 in steady-state FIFO order: kk0 {A,B} then kk1 {A,B}
  STAGE_A(0, 0, 0, 0); STAGE_A(0, 0, 0, 1); STAGE_B(0, 0, 0, 0); STAGE_B(0, 0, 0, 1);
  STAGE_A(0, 0, 1, 0); STAGE_A(0, 0, 1, 1); STAGE_B(0, 0, 1, 0); STAGE_B(0, 0, 1, 1);

  for (int kt = 0; kt < KT; ++kt){
    const int buf = kt & 1;
    const bool more = (kt + 1 < KT);
    bf16x8 af[4], bfr[4];

    // P1 gate: this tile's kk0 (4 oldest) landed; kk1 (4) still in flight
    WAITBAR(4);

    // P1: (mh0, kk0); issue next tile's A-kk0
    if (more){ STAGE_A(buf ^ 1, kt + 1, 0, 0); STAGE_A(buf ^ 1, kt + 1, 0, 1); }
    LDB4(buf, 0, bfr);
    LDA4(buf, 0, 0, af);
    LGK0;
    PHASE_MFMA(0, af, bfr);

    // P2: (mh1, kk0) — kk0 already certified by P1's barrier; issue B-kk0
    if (more){ STAGE_B(buf ^ 1, kt + 1, 0, 0); STAGE_B(buf ^ 1, kt + 1, 0, 1); }
    LDA4(buf, 1, 0, af);
    LGK0;
    PHASE_MFMA(1, af, bfr);

    // P3 gate: this tile's kk1 landed (next tile's kk0 may fly)
    if (more){ WAITBAR(4); } else { WAITBAR(0); }

    // P3: (mh0, kk1); issue next tile's A-kk1
    if (more){ STAGE_A(buf ^ 1, kt + 1, 1, 0); STAGE_A(buf ^ 1, kt + 1, 1, 1); }
    LDB4(buf, 1, bfr);
    LDA4(buf, 0, 1, af);
    LGK0;
    PHASE_MFMA(0, af, bfr);

    // P4: (mh1, kk1); issue B-kk1
    if (more){ STAGE_B(buf ^ 1, kt + 1, 1, 0); STAGE_B(buf ^ 1, kt + 1, 1, 1); }
    LDA4(buf, 1, 1, af);
    LGK0;
    PHASE_MFMA(1, af, bfr);
  }

  // epilogue: C/D layout col = lane&15, row = (lane>>4)*4 + j  [m89-verified]
  #pragma unroll
  for (int m = 0; m < 8; ++m){
    int rbase = row0 + wm * 128 + m * 16 + kl * 4;
    #pragma unroll
    for (int j = 0; j < 4; ++j){
      int rg = rbase + j;
      if (rg < M){
        int dd = 0;
        if (EPI == 3) dd = dstI[rg];
        #pragma unroll
        for (int n = 0; n < 4; ++n){
          int cg = col0 + wn * 64 + n * 16 + lane16;
          float v = acc[m][n][j];
          if (EPI == 0){
            v += bias[cg];
            v = v / (1.f + __expf(-v));
            ((u16*)out)[(size_t)rg * 512 + cg] = f2bf(v);
          } else if (EPI == 3){
            v += bias[cg] + bf2f(G2[(size_t)dd * 512 + cg]);
            v = v / (1.f + __expf(-v));
            ((u16*)out)[(size_t)rg * 512 + cg] = f2bf(v);
          } else if (EPI == 1){
            ((u16*)out)[(size_t)rg * 512 + cg] = f2bf(v);
          } else {
            ((float*)out)[(size_t)rg * 512 + cg] = v;
          }
        }
      }
    }
  }
}

// ---------------- GEMM 128x128 (m97 structure) — small-M GEMMs ----------

template<int MODE, int EPI>
__global__ __launch_bounds__(256)
void k_gemm(const u16* __restrict__ A, const u16* __restrict__ G1, const u16* __restrict__ G2,
            const int* __restrict__ src, const int* __restrict__ dst,
            const u16* __restrict__ Bt, const float* __restrict__ bias,
            void* __restrict__ out, int M, int K)
{
  __shared__ __align__(16) u16 lAx[128 * 64];
  __shared__ __align__(16) u16 lBx[128 * 64];

  const int tid = threadIdx.x;
  const int w = tid >> 6, l = tid & 63;
  const int row0 = blockIdx.x * 128;
  const int col0 = blockIdx.y * 128;

  int srows[4];
  const u16* bptr[4];
  #pragma unroll
  for (int it = 0; it < 4; ++it){
    int r = row0 + it * 32 + w * 8 + (l >> 3);
    if (r >= M) r = M - 1;
    srows[it] = r;
    int n = col0 + it * 32 + w * 8 + (l >> 3);
    bptr[it] = Bt + (size_t)n * K;
  }
  const int kchunk = (l & 7) * 8;

  f32x4 acc[4][4];
  #pragma unroll
  for (int m = 0; m < 4; ++m)
    #pragma unroll
    for (int n = 0; n < 4; ++n)
      acc[m][n] = (f32x4){0.f, 0.f, 0.f, 0.f};

  const int wm = w >> 1, wn = w & 1;
  const int lane16 = l & 15, kl = l >> 4;

  const int KT = K >> 6;
  for (int kt = 0; kt < KT; ++kt){
    const int k0 = kt * 64;
    __syncthreads();
    #pragma unroll
    for (int it = 0; it < 4; ++it){
      const u16* ga;
      if (MODE == 0){
        ga = A + (size_t)srows[it] * K + k0 + kchunk;
      } else {
        int seg = k0 >> 9, klocal = k0 & 511;
        const u16* base = (seg == 0) ? A  + (size_t)srows[it] * 512
                                     : G1 + (size_t)srows[it] * 512;
        ga = base + klocal + kchunk;
      }
      gload_lds16(ga, &lAx[(it * 32 + w * 8) * 64]);
      gload_lds16(bptr[it] + k0 + kchunk, &lBx[(it * 32 + w * 8) * 64]);
    }
    __syncthreads();

    #pragma unroll
    for (int kk = 0; kk < 2; ++kk){
      bf16x8 af[4], bfr[4];
      #pragma unroll
      for (int m = 0; m < 4; ++m)
        af[m] = *(const bf16x8*)&lAx[(wm * 64 + m * 16 + lane16) * 64 + kk * 32 + kl * 8];
      #pragma unroll
      for (int n = 0; n < 4; ++n)
        bfr[n] = *(const bf16x8*)&lBx[(wn * 64 + n * 16 + lane16) * 64 + kk * 32 + kl * 8];
      #pragma unroll
      for (int m = 0; m < 4; ++m)
        #pragma unroll
        for (int n = 0; n < 4; ++n)
          acc[m][n] = __builtin_amdgcn_mfma_f32_16x16x32_bf16(af[m], bfr[n], acc[m][n], 0, 0, 0);
    }
  }

  #pragma unroll
  for (int m = 0; m < 4; ++m){
    int rbase = row0 + wm * 64 + m * 16 + kl * 4;
    #pragma unroll
    for (int n = 0; n < 4; ++n){
      int cg = col0 + wn * 64 + n * 16 + lane16;
      #pragma unroll
      for (int j = 0; j < 4; ++j){
        int rg = rbase + j;
        if (rg < M){
          float v = acc[m][n][j];
          if (EPI == 0){
            v += bias[cg];
            v = v / (1.f + __expf(-v));
            ((u16*)out)[(size_t)rg * 512 + cg] = f2bf(v);
          } else if (EPI == 1){
            ((u16*)out)[(size_t)rg * 512 + cg] = f2bf(v);
          } else {
            ((float*)out)[(size_t)rg * 512 + cg] = v;
          }
        }
      }
    }
  }
}

// ---------------- fused edge-LN + segment-sum: FULLY STREAMING, all-bf16 -------

__global__ __launch_bounds__(256)
void k_agg(const u16* __restrict__ e2, const float* __restrict__ be2,
           const float* __restrict__ ge, const float* __restrict__ bbe,
           const u16* __restrict__ ebf, const int* __restrict__ offs,
           u16* __restrict__ aggbf, int Mn)
{
  int node = blockIdx.x * 4 + (threadIdx.x >> 6);
  int l = threadIdx.x & 63;
  if (node >= Mn) return;
  int p0 = offs[node], p1 = offs[node + 1];

  float b2c[8], gc[8], bbc[8];
  #pragma unroll
  for (int j = 0; j < 8; ++j){
    int c = l * 8 + j;
    b2c[j] = be2[c]; gc[j] = ge[c]; bbc[j] = bbe[c];
  }

  float acc[8] = {0.f,0.f,0.f,0.f,0.f,0.f,0.f,0.f};
  for (int p = p0; p < p1; ++p){
    bf16x8 v  = *(const bf16x8*)(e2  + (size_t)p * 512 + l * 8);
    bf16x8 rv = *(const bf16x8*)(ebf + (size_t)p * 512 + l * 8);
    float x[8], s = 0.f, sq = 0.f;
    #pragma unroll
    for (int j = 0; j < 8; ++j){
      x[j] = bf2f((u16)v[j]) + b2c[j];
      s += x[j]; sq += x[j] * x[j];
    }
    #pragma unroll
    for (int o = 32; o; o >>= 1){ s += __shfl_xor(s, o); sq += __shfl_xor(sq, o); }
    float mean = s * (1.f / 512.f);
    float var = sq * (1.f / 512.f) - mean * mean;
    float rs = rsqrtf(var + 1e-5f);
    #pragma unroll
    for (int j = 0; j < 8; ++j)
      acc[j] += (x[j] - mean) * rs * gc[j] + bbc[j] + bf2f((u16)rv[j]);
  }

  bf16x8 o8;
  #pragma unroll
  for (int j = 0; j < 8; ++j) o8[j] = (short)f2bf(acc[j]);
  *(bf16x8*)(aggbf + (size_t)node * 512 + l * 8) = o8;
}

// ---------------- LayerNorm output kernels ----------------

__global__ __launch_bounds__(256)
void k_ln_out(const float* __restrict__ x2, const float* __restrict__ b2,
              const float* __restrict__ g, const float* __restrict__ bb,
              const float* __restrict__ resid, float* __restrict__ out, int R)
{
  int row = blockIdx.x * 4 + (threadIdx.x >> 6);
  int l = threadIdx.x & 63;
  if (row >= R) return;
  const float* xr = x2 + (size_t)row * 512 + l * 8;
  float4 a = *(const float4*)xr, b4 = *(const float4*)(xr + 4);
  float x[8] = {a.x, a.y, a.z, a.w, b4.x, b4.y, b4.z, b4.w};
  float s = 0.f, sq = 0.f;
  #pragma unroll
  for (int j = 0; j < 8; ++j){
    x[j] += b2[l * 8 + j];
    s += x[j]; sq += x[j] * x[j];
  }
  #pragma unroll
  for (int o = 32; o; o >>= 1){ s += __shfl_xor(s, o); sq += __shfl_xor(sq, o); }
  float mean = s * (1.f / 512.f);
  float var = sq * (1.f / 512.f) - mean * mean;
  float rs = rsqrtf(var + 1e-5f);
  const float* rr = resid + (size_t)row * 512 + l * 8;
  float* po = out + (size_t)row * 512 + l * 8;
  #pragma unroll
  for (int j = 0; j < 8; ++j){
    int c = l * 8 + j;
    po[j] = (x[j] - mean) * rs * g[c] + bb[c] + rr[j];
  }
}

// x2 AND residual in bf16 (grid path)
__global__ __launch_bounds__(256)
void k_ln_out_bb(const u16* __restrict__ x2, const float* __restrict__ b2,
                 const float* __restrict__ g, const float* __restrict__ bb,
                 const u16* __restrict__ resid, float* __restrict__ out, int R)
{
  int row = blockIdx.x * 4 + (threadIdx.x >> 6);
  int l = threadIdx.x & 63;
  if (row >= R) return;
  bf16x8 xv = *(const bf16x8*)(x2 + (size_t)row * 512 + l * 8);
  float x[8], s = 0.f, sq = 0.f;
  #pragma unroll
  for (int j = 0; j < 8; ++j){
    x[j] = bf2f((u16)xv[j]) + b2[l * 8 + j];
    s += x[j]; sq += x[j] * x[j];
  }
  #pragma unroll
  for (int o = 32; o; o >>= 1){ s += __shfl_xor(s, o); sq += __shfl_xor(sq, o); }
  float mean = s * (1.f / 512.f);
  float var = sq * (1.f / 512.f) - mean * mean;
  float rs = rsqrtf(var + 1e-5f);
  bf16x8 rv = *(const bf16x8*)(resid + (size_t)row * 512 + l * 8);
  float* po = out + (size_t)row * 512 + l * 8;
  #pragma unroll
  for (int j = 0; j < 8; ++j){
    int c = l * 8 + j;
    po[j] = (x[j] - mean) * rs * g[c] + bb[c] + bf2f((u16)rv[j]);
  }
}

// ---------------- launch ----------------

extern "C" void kernel_launch(void* const* d_in, const int* in_sizes, int n_in,
                              void* d_out, int out_size, void* d_ws, size_t ws_size,
                              hipStream_t stream)
{
  const int N_GRID = 65536, N_MESH = 10242, N_EDGE = 131072, H = 512;

  const float* grid_f = (const float*)d_in[0];
  const float* mesh_f = (const float*)d_in[1];
  const float* edge_f = (const float*)d_in[2];
  const int*   src    = (const int*)d_in[3];
  const int*   dst    = (const int*)d_in[4];
  const float* We1 = (const float*)d_in[5];  const float* be1 = (const float*)d_in[6];
  const float* We2 = (const float*)d_in[7];  const float* be2 = (const float*)d_in[8];
  const float* ge  = (const float*)d_in[9];  const float* bbe = (const float*)d_in[10];
  const float* Wn1 = (const float*)d_in[11]; const float* bn1 = (const float*)d_in[12];
  const float* Wn2 = (const float*)d_in[13]; const float* bn2 = (const float*)d_in[14];
  const float* gn  = (const float*)d_in[15]; const float* bbn = (const float*)d_in[16];
  const float* Wg1 = (const float*)d_in[17]; const float* bg1 = (const float*)d_in[18];
  const float* Wg2 = (const float*)d_in[19]; const float* bg2 = (const float*)d_in[20];
  const float* gg  = (const float*)d_in[21]; const float* bbg = (const float*)d_in[22];

  u8* ws = (u8*)d_ws;
  const size_t MiB = 1u << 20;
  u16*  Gbf   = (u16*)(ws + 0);          //  64 MiB  grid bf16 (live whole run)
  u16*  Mbf   = (u16*)(ws + 64  * MiB);  //  10 MiB  mesh bf16
  u16*  AggBf = (u16*)(ws + 75  * MiB);  //  10 MiB  agg bf16
  // weights (bf16, transposed) at 86 MiB
  u16*  We1t  = (u16*)(ws + 86  * MiB);              // [512][1024]
  u16*  Wpm   = (u16*)(ws + 86  * MiB + 1048576);    // [512][512]
  u16*  We2t  = (u16*)(ws + 86  * MiB + 1572864);
  u16*  Wn1t  = (u16*)(ws + 86  * MiB + 2097152);
  u16*  Wn2t  = (u16*)(ws + 86  * MiB + 3145728);
  u16*  Wg1t  = (u16*)(ws + 86  * MiB + 3670016);
  u16*  Wg2t  = (u16*)(ws + 86  * MiB + 4194304);
  // dst-sort scratch at 91 MiB
  int*  offs_d = (int*)(ws + 91 * MiB);               // 10243
  int*  cnt_d  = (int*)(ws + 91 * MiB) + 10496;       // 10242
  int*  cur_d  = (int*)(ws + 91 * MiB) + 20992;       // 10242
  // index maps at 92 MiB
  int*  pos_d  = (int*)(ws + 92 * MiB);               // 131072
  int*  srcD   = (int*)(ws + 92 * MiB) + 131072;      // 131072
  int*  dstD   = (int*)(ws + 92 * MiB) + 262144;      // 131072 (ends < 94 MiB)
  u16*  Pm    = (u16*)(ws + 96 * MiB);   //  10 MiB  mesh-term precompute
  u16*  He    = (u16*)(ws + 112 * MiB);  // 128 MiB  He / Hn / Hg
  u8*   Big   =  ws + 240 * MiB;         // 128 MiB  Ebf (persists thru k_agg) -> N2 -> G2
  u16*  Ebf   = (u16*)Big;
  float* N2   = (float*)Big;
  u16*  G2    = (u16*)Big;

  float* grid_out = (float*)d_out;
  float* mesh_out = (float*)d_out + (size_t)N_GRID * H;
  // E2 scratch in d_out's grid_out region (exact fit; consumed by k_agg before
  // ln_out_bb writes grid_out)
  u16*  E2    = (u16*)d_out;

  // 1) dst-sort + fused index maps
  k_zero_i32<<<(20992 + 255) / 256, 256, 0, stream>>>(cnt_d, 20992);   // cnt_d + cur_d
  k_hist<<<N_EDGE / 256, 256, 0, stream>>>(dst, cnt_d, N_EDGE);
  k_scan<<<1, 1024, 0, stream>>>(cnt_d, offs_d, N_MESH);
  k_scatter_pos<<<N_EDGE / 256, 256, 0, stream>>>(dst, src, offs_d, cur_d, pos_d, srcD, dstD, N_EDGE);

  // 2) conversions + weight prep (Ebf permuted to dst-order)
  k_f32_to_bf16<<<2048, 256, 0, stream>>>(grid_f, Gbf, (long)N_GRID * H);
  k_f32_to_bf16<<<1024, 256, 0, stream>>>(mesh_f, Mbf, (long)N_MESH * H);
  k_conv_perm<<<N_EDGE / 4, 256, 0, stream>>>(edge_f, pos_d, Ebf, N_EDGE);
  k_transpose_w_off<<<(1024 * 512 + 255) / 256, 256, 0, stream>>>(We1, We1t, 1024, 512, 0);
  k_transpose_w_off<<<(512  * 512 + 255) / 256, 256, 0, stream>>>(We1, Wpm, 512, 512, 1024);
  k_transpose_w_off<<<(512  * 512 + 255) / 256, 256, 0, stream>>>(We2, We2t, 512, 512, 0);
  k_transpose_w_off<<<(1024 * 512 + 255) / 256, 256, 0, stream>>>(Wn1, Wn1t, 1024, 512, 0);
  k_transpose_w_off<<<(512  * 512 + 255) / 256, 256, 0, stream>>>(Wn2, Wn2t, 512, 512, 0);
  k_transpose_w_off<<<(512  * 512 + 255) / 256, 256, 0, stream>>>(Wg1, Wg1t, 512, 512, 0);
  k_transpose_w_off<<<(512  * 512 + 255) / 256, 256, 0, stream>>>(Wg2, Wg2t, 512, 512, 0);

  // 3) mesh-term precompute: Pm = Mbf * We1[1024:1536]
  dim3 gpm((N_MESH + 127) / 128, 4);
  k_gemm<0, 1><<<gpm, 256, 0, stream>>>(Mbf, nullptr, nullptr, nullptr, nullptr, Wpm, nullptr, Pm, N_MESH, 512);

  // 4) edge MLP in dst-sorted row order; E2 -> d_out scratch
  dim3 ge1(2, N_EDGE / 256);
  k_gemm256<1, 3><<<ge1, 512, 0, stream>>>(Ebf, Gbf, Pm, srcD, dstD, We1t, be1, He, N_EDGE, 1024);
  k_gemm256<0, 1><<<ge1, 512, 0, stream>>>(He, nullptr, nullptr, nullptr, nullptr, We2t, nullptr, E2, N_EDGE, 512);
  k_agg<<<(N_MESH + 3) / 4, 256, 0, stream>>>(E2, be2, ge, bbe, Ebf, offs_d, AggBf, N_MESH);

  // 5) node MLP
  dim3 gn1((N_MESH + 127) / 128, 4);
  k_gemm<1, 0><<<gn1, 256, 0, stream>>>(Mbf, AggBf, nullptr, nullptr, nullptr, Wn1t, bn1, He, N_MESH, 1024);
  k_gemm<0, 2><<<gn1, 256, 0, stream>>>(He, nullptr, nullptr, nullptr, nullptr, Wn2t, nullptr, N2, N_MESH, 512);
  k_ln_out<<<(N_MESH + 3) / 4, 256, 0, stream>>>(N2, bn2, gn, bbn, mesh_f, mesh_out, N_MESH);

  // 6) grid MLP (G2 bf16 in Big; grid_out written last)
  dim3 gg1(2, N_GRID / 256);
  k_gemm256<0, 0><<<gg1, 512, 0, stream>>>(Gbf, nullptr, nullptr, nullptr, nullptr, Wg1t, bg1, He, N_GRID, 512);
  k_gemm256<0, 1><<<gg1, 512, 0, stream>>>(He, nullptr, nullptr, nullptr, nullptr, Wg2t, nullptr, G2, N_GRID, 512);
  k_ln_out_bb<<<N_GRID / 4, 256, 0, stream>>>(G2, bg2, gg, bbg, Gbf, grid_out, N_GRID);
}

// Round 16
// 880.401 us; speedup vs baseline: 1.0560x; 1.0560x over previous
//
#include <hip/hip_runtime.h>
#include <stdint.h>

typedef unsigned short u16;
typedef unsigned int   u32;
typedef unsigned char  u8;

using bf16x8 = __attribute__((ext_vector_type(8))) short;
using f32x4  = __attribute__((ext_vector_type(4))) float;

#define DEVF static __device__ __forceinline__

DEVF u16 f2bf(float f){
  u32 u = __builtin_bit_cast(u32, f);
  u32 r = u + 0x7FFFu + ((u >> 16) & 1u);
  return (u16)(r >> 16);
}
DEVF float bf2f(u16 h){
  u32 u = ((u32)h) << 16;
  return __builtin_bit_cast(float, u);
}

DEVF void gload_lds16(const u16* g, u16* s){
  __builtin_amdgcn_global_load_lds(
      (const __attribute__((address_space(1))) u32*)g,
      (__attribute__((address_space(3))) u32*)(u32)(uintptr_t)s,
      16, 0, 0);
}

// ---------------- conversion / utility kernels ----------------

// merged grid+mesh f32 -> bf16 (one launch)
__global__ __launch_bounds__(256)
void k_conv2(const float* __restrict__ ga, u16* __restrict__ go, long ng,
             const float* __restrict__ mb, u16* __restrict__ mo, long nm){
  long i = ((long)blockIdx.x * 256 + threadIdx.x) * 8;
  const float* in; u16* out; long n;
  if (i < ng){ in = ga; out = go; n = ng; }
  else { i -= ng; in = mb; out = mo; n = nm; }
  if (i >= n) return;
  float4 a = *(const float4*)(in + i);
  float4 b = *(const float4*)(in + i + 4);
  bf16x8 v;
  v[0]=(short)f2bf(a.x); v[1]=(short)f2bf(a.y); v[2]=(short)f2bf(a.z); v[3]=(short)f2bf(a.w);
  v[4]=(short)f2bf(b.x); v[5]=(short)f2bf(b.y); v[6]=(short)f2bf(b.z); v[7]=(short)f2bf(b.w);
  *(bf16x8*)(out + i) = v;
}

// edge_f[e] (f32 row) -> Ebf[pos[e]] (bf16 row): permuted conversion (dst-order)
__global__ __launch_bounds__(256)
void k_conv_perm(const float* __restrict__ in, const int* __restrict__ pos,
                 u16* __restrict__ out, int E){
  int e = blockIdx.x * 4 + (threadIdx.x >> 6);
  int l = threadIdx.x & 63;
  if (e >= E) return;
  const float* r = in + (size_t)e * 512 + l * 8;
  float4 a = *(const float4*)r, b = *(const float4*)(r + 4);
  bf16x8 v;
  v[0]=(short)f2bf(a.x); v[1]=(short)f2bf(a.y); v[2]=(short)f2bf(a.z); v[3]=(short)f2bf(a.w);
  v[4]=(short)f2bf(b.x); v[5]=(short)f2bf(b.y); v[6]=(short)f2bf(b.z); v[7]=(short)f2bf(b.w);
  *(bf16x8*)(out + (size_t)pos[e] * 512 + l * 8) = v;
}

__global__ __launch_bounds__(256) void k_zero_i32(int* __restrict__ p, int n){
  int i = blockIdx.x * 256 + threadIdx.x;
  if (i < n) p[i] = 0;
}

// ---- merged weight prep: all 7 transposed-bf16 weight regions in ONE launch.
// seg layout (N=512 always): Wt[n*K + k] = f2bf(W[(k + k0)*512 + n])
__global__ __launch_bounds__(256)
void k_prep_w(const float* __restrict__ We1, const float* __restrict__ We2,
              const float* __restrict__ Wn1, const float* __restrict__ Wn2,
              const float* __restrict__ Wg1, const float* __restrict__ Wg2,
              u16* __restrict__ We1t, u16* __restrict__ Wpm,
              u16* __restrict__ We2t, u16* __restrict__ Wn1t,
              u16* __restrict__ Wn2t, u16* __restrict__ Wg1t,
              u16* __restrict__ Wg2t)
{
  int idx = blockIdx.x * 256 + threadIdx.x;
  const int S0 = 512 * 1024;          // We1t  (k0=0,    K=1024)
  const int S1 = S0 + 512 * 512;      // Wpm   (k0=1024, K=512)
  const int S2 = S1 + 512 * 512;      // We2t
  const int S3 = S2 + 512 * 1024;     // Wn1t  (K=1024)
  const int S4 = S3 + 512 * 512;      // Wn2t
  const int S5 = S4 + 512 * 512;      // Wg1t
  const int S6 = S5 + 512 * 512;      // Wg2t
  if (idx >= S6) return;
  const float* W; u16* Wt; int K, k0, loc;
  if (idx < S0){ W = We1; Wt = We1t; K = 1024; k0 = 0;    loc = idx; }
  else if (idx < S1){ W = We1; Wt = Wpm;  K = 512; k0 = 1024; loc = idx - S0; }
  else if (idx < S2){ W = We2; Wt = We2t; K = 512; k0 = 0;    loc = idx - S1; }
  else if (idx < S3){ W = Wn1; Wt = Wn1t; K = 1024; k0 = 0;   loc = idx - S2; }
  else if (idx < S4){ W = Wn2; Wt = Wn2t; K = 512; k0 = 0;    loc = idx - S3; }
  else if (idx < S5){ W = Wg1; Wt = Wg1t; K = 512; k0 = 0;    loc = idx - S4; }
  else { W = Wg2; Wt = Wg2t; K = 512; k0 = 0; loc = idx - S5; }
  int k = loc >> 9, n = loc & 511;            // N = 512 for all
  Wt[(size_t)n * K + k] = f2bf(W[(size_t)(k + k0) * 512 + n]);
}

// ---------------- counting sort (dst only) ----------------

__global__ __launch_bounds__(256)
void k_hist(const int* __restrict__ key, int* __restrict__ cnt, int E){
  int e = blockIdx.x * 256 + threadIdx.x;
  if (e < E) atomicAdd(&cnt[key[e]], 1);
}

__global__ __launch_bounds__(1024)
void k_scan(const int* __restrict__ cnt, int* __restrict__ offs, int n){
  __shared__ int part[1024];
  int t = threadIdx.x;
  const int PER = (n + 1023) / 1024;
  int base = t * PER;
  int s = 0;
  for (int i = 0; i < PER; ++i){ int idx = base + i; if (idx < n) s += cnt[idx]; }
  part[t] = s;
  __syncthreads();
  for (int o = 1; o < 1024; o <<= 1){
    int v = (t >= o) ? part[t - o] : 0;
    __syncthreads();
    part[t] += v;
    __syncthreads();
  }
  int run = (t == 0) ? 0 : part[t - 1];
  for (int i = 0; i < PER; ++i){
    int idx = base + i;
    if (idx < n){ offs[idx] = run; run += cnt[idx]; }
  }
  if (t == 1023) offs[n] = part[1023];
}

// scatter + inverse permutation + sorted index maps, fused
__global__ __launch_bounds__(256)
void k_scatter_pos(const int* __restrict__ key, const int* __restrict__ srcIn,
                   const int* __restrict__ offs, int* __restrict__ cur,
                   int* __restrict__ pos, int* __restrict__ srcD,
                   int* __restrict__ dstD, int E){
  int e = blockIdx.x * 256 + threadIdx.x;
  if (e < E){
    int d = key[e];
    int p = offs[d] + atomicAdd(&cur[d], 1);
    pos[e] = p;
    srcD[p] = srcIn[e];
    dstD[p] = d;
  }
}

// ============ GEMM 256x256, BK=64, 8 waves, early-issue + single barrier =======
// r14-VERIFIED variant (899.9 us total, e1=266us, conflicts=0, FETCH=151MB).
// T2 both-sides swizzle. T5 setprio. T1 = r8-verified chunked XCD swizzle.
// r13 lesson: NO min-waves launch_bounds (acc[8][4] = 128 VGPR; capping spills).
// r15 lesson: half-tile counted vmcnt(4) is NULL here — whole-tile drain kept.
// MODE 0: A[M][K]. MODE 1 (edge, K=1024): k<512 -> A[r], else G1[srcI[r]].
// EPI 0: silu(v+bias)->bf16. 1: raw bf16. 2: raw f32. 3: silu(v+bias+Pm[dstI[r]])->bf16.

#define LDA4(BUF, MH, KK, AF) \
  _Pragma("unroll") for (int m_ = 0; m_ < 4; ++m_) \
    AF[m_] = *(const bf16x8*)&lA[BUF][(wm * 128 + (MH) * 64 + m_ * 16 + lane16) * 64 + \
                                      ((((KK) << 2) | kl) ^ (lane16 & 7)) * 8];

#define LDB4(BUF, KK, BFR) \
  _Pragma("unroll") for (int n_ = 0; n_ < 4; ++n_) \
    BFR[n_] = *(const bf16x8*)&lB[BUF][(wn * 64 + n_ * 16 + lane16) * 64 + \
                                       ((((KK) << 2) | kl) ^ (lane16 & 7)) * 8];

#define PHASE_MFMA(MH, AF, BFR) \
  __builtin_amdgcn_s_setprio(1); \
  _Pragma("unroll") for (int m_ = 0; m_ < 4; ++m_) \
    _Pragma("unroll") for (int n_ = 0; n_ < 4; ++n_) \
      acc[(MH) * 4 + m_][n_] = __builtin_amdgcn_mfma_f32_16x16x32_bf16( \
          AF[m_], BFR[n_], acc[(MH) * 4 + m_][n_], 0, 0, 0); \
  __builtin_amdgcn_s_setprio(0);

#define STAGE_A(BUF, KT_, RND) do{ \
    const int k0_ = (KT_) * 64; \
    const u16* ga_; \
    if (MODE == 0){ ga_ = A + (size_t)srows[RND] * K + k0_ + kchunk; } \
    else { \
      int seg_ = k0_ >> 9, klo_ = k0_ & 511; \
      const u16* b_ = (seg_ == 0) ? A  + (size_t)srows[RND] * 512 \
                                  : G1 + (size_t)sidx1[RND] * 512; \
      ga_ = b_ + klo_ + kchunk; \
    } \
    gload_lds16(ga_, &lA[BUF][((RND) * 64 + w * 8) * 64]); \
  }while(0)

#define STAGE_B(BUF, KT_, RND) \
  gload_lds16(bptr[RND] + (KT_) * 64 + kchunk, &lB[BUF][((RND) * 64 + w * 8) * 64])

#define STAGE8(BUF, KT_) do{ \
    STAGE_A(BUF, KT_, 0); STAGE_A(BUF, KT_, 1); STAGE_A(BUF, KT_, 2); STAGE_A(BUF, KT_, 3); \
    STAGE_B(BUF, KT_, 0); STAGE_B(BUF, KT_, 1); STAGE_B(BUF, KT_, 2); STAGE_B(BUF, KT_, 3); \
  }while(0)

#define WAITBAR(N) do{ \
    asm volatile("s_waitcnt vmcnt(" #N ")" ::: "memory"); \
    __builtin_amdgcn_s_barrier(); \
    __builtin_amdgcn_sched_barrier(0); \
  }while(0)

template<int MODE, int EPI>
__global__ __launch_bounds__(512)
void k_gemm256(const u16* __restrict__ A, const u16* __restrict__ G1, const u16* __restrict__ G2,
               const int* __restrict__ srcI, const int* __restrict__ dstI,
               const u16* __restrict__ Bt, const float* __restrict__ bias,
               void* __restrict__ out, int M, int K)
{
  __shared__ __align__(16) u16 lA[2][256 * 64];
  __shared__ __align__(16) u16 lB[2][256 * 64];

  const int tid = threadIdx.x;
  const int w = tid >> 6, l = tid & 63;

  // T1 (r8-verified)
  const int nwg = gridDim.x * gridDim.y;
  const int wgf = blockIdx.y * gridDim.x + blockIdx.x;
  const int lg  = (wgf & 7) * (nwg >> 3) + (wgf >> 3);
  const int col0 = (lg % gridDim.x) * 256;
  const int row0 = (lg / gridDim.x) * 256;

  int srows[4], sidx1[4];
  const u16* bptr[4];
  #pragma unroll
  for (int it = 0; it < 4; ++it){
    int r = row0 + it * 64 + w * 8 + (l >> 3);
    if (r >= M) r = M - 1;
    srows[it] = r;
    if (MODE == 1){ sidx1[it] = srcI[r]; }
    int n = col0 + it * 64 + w * 8 + (l >> 3);
    bptr[it] = Bt + (size_t)n * K;
  }
  const int kchunk = ((l & 7) ^ (l >> 3)) * 8;   // T2 inverse-swizzled source

  f32x4 acc[8][4];
  #pragma unroll
  for (int m = 0; m < 8; ++m)
    #pragma unroll
    for (int n = 0; n < 4; ++n)
      acc[m][n] = (f32x4){0.f, 0.f, 0.f, 0.f};

  const int wm = w >> 2, wn = w & 3;       // 2 x 4 wave grid
  const int lane16 = l & 15, kl = l >> 4;

  const int KT = K >> 6;

  STAGE8(0, 0);

  for (int kt = 0; kt < KT; ++kt){
    const int buf = kt & 1;

    WAITBAR(0);

    if (kt + 1 < KT){ STAGE8(buf ^ 1, kt + 1); }
    __builtin_amdgcn_sched_barrier(0);

    bf16x8 af[4], bfr[4];
    LDB4(buf, 0, bfr);
    LDA4(buf, 0, 0, af);
    PHASE_MFMA(0, af, bfr);

    LDA4(buf, 1, 0, af);
    PHASE_MFMA(1, af, bfr);

    LDB4(buf, 1, bfr);
    LDA4(buf, 0, 1, af);
    PHASE_MFMA(0, af, bfr);

    LDA4(buf, 1, 1, af);
    PHASE_MFMA(1, af, bfr);
  }

  // epilogue: C/D layout col = lane&15, row = (lane>>4)*4 + j  [m89-verified]
  #pragma unroll
  for (int m = 0; m < 8; ++m){
    int rbase = row0 + wm * 128 + m * 16 + kl * 4;
    #pragma unroll
    for (int j = 0; j < 4; ++j){
      int rg = rbase + j;
      if (rg < M){
        int dd = 0;
        if (EPI == 3) dd = dstI[rg];
        #pragma unroll
        for (int n = 0; n < 4; ++n){
          int cg = col0 + wn * 64 + n * 16 + lane16;
          float v = acc[m][n][j];
          if (EPI == 0){
            v += bias[cg];
            v = v / (1.f + __expf(-v));
            ((u16*)out)[(size_t)rg * 512 + cg] = f2bf(v);
          } else if (EPI == 3){
            v += bias[cg] + bf2f(G2[(size_t)dd * 512 + cg]);
            v = v / (1.f + __expf(-v));
            ((u16*)out)[(size_t)rg * 512 + cg] = f2bf(v);
          } else if (EPI == 1){
            ((u16*)out)[(size_t)rg * 512 + cg] = f2bf(v);
          } else {
            ((float*)out)[(size_t)rg * 512 + cg] = v;
          }
        }
      }
    }
  }
}

// ---------------- GEMM 128x128 (m97 structure) — small-M GEMMs ----------

template<int MODE, int EPI>
__global__ __launch_bounds__(256)
void k_gemm(const u16* __restrict__ A, const u16* __restrict__ G1, const u16* __restrict__ G2,
            const int* __restrict__ src, const int* __restrict__ dst,
            const u16* __restrict__ Bt, const float* __restrict__ bias,
            void* __restrict__ out, int M, int K)
{
  __shared__ __align__(16) u16 lAx[128 * 64];
  __shared__ __align__(16) u16 lBx[128 * 64];

  const int tid = threadIdx.x;
  const int w = tid >> 6, l = tid & 63;
  const int row0 = blockIdx.x * 128;
  const int col0 = blockIdx.y * 128;

  int srows[4];
  const u16* bptr[4];
  #pragma unroll
  for (int it = 0; it < 4; ++it){
    int r = row0 + it * 32 + w * 8 + (l >> 3);
    if (r >= M) r = M - 1;
    srows[it] = r;
    int n = col0 + it * 32 + w * 8 + (l >> 3);
    bptr[it] = Bt + (size_t)n * K;
  }
  const int kchunk = (l & 7) * 8;

  f32x4 acc[4][4];
  #pragma unroll
  for (int m = 0; m < 4; ++m)
    #pragma unroll
    for (int n = 0; n < 4; ++n)
      acc[m][n] = (f32x4){0.f, 0.f, 0.f, 0.f};

  const int wm = w >> 1, wn = w & 1;
  const int lane16 = l & 15, kl = l >> 4;

  const int KT = K >> 6;
  for (int kt = 0; kt < KT; ++kt){
    const int k0 = kt * 64;
    __syncthreads();
    #pragma unroll
    for (int it = 0; it < 4; ++it){
      const u16* ga;
      if (MODE == 0){
        ga = A + (size_t)srows[it] * K + k0 + kchunk;
      } else {
        int seg = k0 >> 9, klocal = k0 & 511;
        const u16* base = (seg == 0) ? A  + (size_t)srows[it] * 512
                                     : G1 + (size_t)srows[it] * 512;
        ga = base + klocal + kchunk;
      }
      gload_lds16(ga, &lAx[(it * 32 + w * 8) * 64]);
      gload_lds16(bptr[it] + k0 + kchunk, &lBx[(it * 32 + w * 8) * 64]);
    }
    __syncthreads();

    #pragma unroll
    for (int kk = 0; kk < 2; ++kk){
      bf16x8 af[4], bfr[4];
      #pragma unroll
      for (int m = 0; m < 4; ++m)
        af[m] = *(const bf16x8*)&lAx[(wm * 64 + m * 16 + lane16) * 64 + kk * 32 + kl * 8];
      #pragma unroll
      for (int n = 0; n < 4; ++n)
        bfr[n] = *(const bf16x8*)&lBx[(wn * 64 + n * 16 + lane16) * 64 + kk * 32 + kl * 8];
      #pragma unroll
      for (int m = 0; m < 4; ++m)
        #pragma unroll
        for (int n = 0; n < 4; ++n)
          acc[m][n] = __builtin_amdgcn_mfma_f32_16x16x32_bf16(af[m], bfr[n], acc[m][n], 0, 0, 0);
    }
  }

  #pragma unroll
  for (int m = 0; m < 4; ++m){
    int rbase = row0 + wm * 64 + m * 16 + kl * 4;
    #pragma unroll
    for (int n = 0; n < 4; ++n){
      int cg = col0 + wn * 64 + n * 16 + lane16;
      #pragma unroll
      for (int j = 0; j < 4; ++j){
        int rg = rbase + j;
        if (rg < M){
          float v = acc[m][n][j];
          if (EPI == 0){
            v += bias[cg];
            v = v / (1.f + __expf(-v));
            ((u16*)out)[(size_t)rg * 512 + cg] = f2bf(v);
          } else if (EPI == 1){
            ((u16*)out)[(size_t)rg * 512 + cg] = f2bf(v);
          } else {
            ((float*)out)[(size_t)rg * 512 + cg] = v;
          }
        }
      }
    }
  }
}

// ---------------- fused edge-LN + segment-sum: FULLY STREAMING, all-bf16 -------

__global__ __launch_bounds__(256)
void k_agg(const u16* __restrict__ e2, const float* __restrict__ be2,
           const float* __restrict__ ge, const float* __restrict__ bbe,
           const u16* __restrict__ ebf, const int* __restrict__ offs,
           u16* __restrict__ aggbf, int Mn)
{
  int node = blockIdx.x * 4 + (threadIdx.x >> 6);
  int l = threadIdx.x & 63;
  if (node >= Mn) return;
  int p0 = offs[node], p1 = offs[node + 1];

  float b2c[8], gc[8], bbc[8];
  #pragma unroll
  for (int j = 0; j < 8; ++j){
    int c = l * 8 + j;
    b2c[j] = be2[c]; gc[j] = ge[c]; bbc[j] = bbe[c];
  }

  float acc[8] = {0.f,0.f,0.f,0.f,0.f,0.f,0.f,0.f};
  for (int p = p0; p < p1; ++p){
    bf16x8 v  = *(const bf16x8*)(e2  + (size_t)p * 512 + l * 8);
    bf16x8 rv = *(const bf16x8*)(ebf + (size_t)p * 512 + l * 8);
    float x[8], s = 0.f, sq = 0.f;
    #pragma unroll
    for (int j = 0; j < 8; ++j){
      x[j] = bf2f((u16)v[j]) + b2c[j];
      s += x[j]; sq += x[j] * x[j];
    }
    #pragma unroll
    for (int o = 32; o; o >>= 1){ s += __shfl_xor(s, o); sq += __shfl_xor(sq, o); }
    float mean = s * (1.f / 512.f);
    float var = sq * (1.f / 512.f) - mean * mean;
    float rs = rsqrtf(var + 1e-5f);
    #pragma unroll
    for (int j = 0; j < 8; ++j)
      acc[j] += (x[j] - mean) * rs * gc[j] + bbc[j] + bf2f((u16)rv[j]);
  }

  bf16x8 o8;
  #pragma unroll
  for (int j = 0; j < 8; ++j) o8[j] = (short)f2bf(acc[j]);
  *(bf16x8*)(aggbf + (size_t)node * 512 + l * 8) = o8;
}

// ---------------- LayerNorm output kernels ----------------

__global__ __launch_bounds__(256)
void k_ln_out(const float* __restrict__ x2, const float* __restrict__ b2,
              const float* __restrict__ g, const float* __restrict__ bb,
              const float* __restrict__ resid, float* __restrict__ out, int R)
{
  int row = blockIdx.x * 4 + (threadIdx.x >> 6);
  int l = threadIdx.x & 63;
  if (row >= R) return;
  const float* xr = x2 + (size_t)row * 512 + l * 8;
  float4 a = *(const float4*)xr, b4 = *(const float4*)(xr + 4);
  float x[8] = {a.x, a.y, a.z, a.w, b4.x, b4.y, b4.z, b4.w};
  float s = 0.f, sq = 0.f;
  #pragma unroll
  for (int j = 0; j < 8; ++j){
    x[j] += b2[l * 8 + j];
    s += x[j]; sq += x[j] * x[j];
  }
  #pragma unroll
  for (int o = 32; o; o >>= 1){ s += __shfl_xor(s, o); sq += __shfl_xor(sq, o); }
  float mean = s * (1.f / 512.f);
  float var = sq * (1.f / 512.f) - mean * mean;
  float rs = rsqrtf(var + 1e-5f);
  const float* rr = resid + (size_t)row * 512 + l * 8;
  float* po = out + (size_t)row * 512 + l * 8;
  #pragma unroll
  for (int j = 0; j < 8; ++j){
    int c = l * 8 + j;
    po[j] = (x[j] - mean) * rs * g[c] + bb[c] + rr[j];
  }
}

// x2 AND residual in bf16 (grid path)
__global__ __launch_bounds__(256)
void k_ln_out_bb(const u16* __restrict__ x2, const float* __restrict__ b2,
                 const float* __restrict__ g, const float* __restrict__ bb,
                 const u16* __restrict__ resid, float* __restrict__ out, int R)
{
  int row = blockIdx.x * 4 + (threadIdx.x >> 6);
  int l = threadIdx.x & 63;
  if (row >= R) return;
  bf16x8 xv = *(const bf16x8*)(x2 + (size_t)row * 512 + l * 8);
  float x[8], s = 0.f, sq = 0.f;
  #pragma unroll
  for (int j = 0; j < 8; ++j){
    x[j] = bf2f((u16)xv[j]) + b2[l * 8 + j];
    s += x[j]; sq += x[j] * x[j];
  }
  #pragma unroll
  for (int o = 32; o; o >>= 1){ s += __shfl_xor(s, o); sq += __shfl_xor(sq, o); }
  float mean = s * (1.f / 512.f);
  float var = sq * (1.f / 512.f) - mean * mean;
  float rs = rsqrtf(var + 1e-5f);
  bf16x8 rv = *(const bf16x8*)(resid + (size_t)row * 512 + l * 8);
  float* po = out + (size_t)row * 512 + l * 8;
  #pragma unroll
  for (int j = 0; j < 8; ++j){
    int c = l * 8 + j;
    po[j] = (x[j] - mean) * rs * g[c] + bb[c] + bf2f((u16)rv[j]);
  }
}

// ---------------- launch ----------------

extern "C" void kernel_launch(void* const* d_in, const int* in_sizes, int n_in,
                              void* d_out, int out_size, void* d_ws, size_t ws_size,
                              hipStream_t stream)
{
  const int N_GRID = 65536, N_MESH = 10242, N_EDGE = 131072, H = 512;

  const float* grid_f = (const float*)d_in[0];
  const float* mesh_f = (const float*)d_in[1];
  const float* edge_f = (const float*)d_in[2];
  const int*   src    = (const int*)d_in[3];
  const int*   dst    = (const int*)d_in[4];
  const float* We1 = (const float*)d_in[5];  const float* be1 = (const float*)d_in[6];
  const float* We2 = (const float*)d_in[7];  const float* be2 = (const float*)d_in[8];
  const float* ge  = (const float*)d_in[9];  const float* bbe = (const float*)d_in[10];
  const float* Wn1 = (const float*)d_in[11]; const float* bn1 = (const float*)d_in[12];
  const float* Wn2 = (const float*)d_in[13]; const float* bn2 = (const float*)d_in[14];
  const float* gn  = (const float*)d_in[15]; const float* bbn = (const float*)d_in[16];
  const float* Wg1 = (const float*)d_in[17]; const float* bg1 = (const float*)d_in[18];
  const float* Wg2 = (const float*)d_in[19]; const float* bg2 = (const float*)d_in[20];
  const float* gg  = (const float*)d_in[21]; const float* bbg = (const float*)d_in[22];

  u8* ws = (u8*)d_ws;
  const size_t MiB = 1u << 20;
  u16*  Gbf   = (u16*)(ws + 0);          //  64 MiB  grid bf16 (live whole run)
  u16*  Mbf   = (u16*)(ws + 64  * MiB);  //  10 MiB  mesh bf16
  u16*  AggBf = (u16*)(ws + 75  * MiB);  //  10 MiB  agg bf16
  // weights (bf16, transposed) at 86 MiB
  u16*  We1t  = (u16*)(ws + 86  * MiB);              // [512][1024]
  u16*  Wpm   = (u16*)(ws + 86  * MiB + 1048576);    // [512][512]
  u16*  We2t  = (u16*)(ws + 86  * MiB + 1572864);
  u16*  Wn1t  = (u16*)(ws + 86  * MiB + 2097152);
  u16*  Wn2t  = (u16*)(ws + 86  * MiB + 3145728);
  u16*  Wg1t  = (u16*)(ws + 86  * MiB + 3670016);
  u16*  Wg2t  = (u16*)(ws + 86  * MiB + 4194304);
  // dst-sort scratch at 91 MiB
  int*  offs_d = (int*)(ws + 91 * MiB);               // 10243
  int*  cnt_d  = (int*)(ws + 91 * MiB) + 10496;       // 10242
  int*  cur_d  = (int*)(ws + 91 * MiB) + 20992;       // 10242
  // index maps at 92 MiB
  int*  pos_d  = (int*)(ws + 92 * MiB);               // 131072
  int*  srcD   = (int*)(ws + 92 * MiB) + 131072;      // 131072
  int*  dstD   = (int*)(ws + 92 * MiB) + 262144;      // 131072 (ends < 94 MiB)
  u16*  Pm    = (u16*)(ws + 96 * MiB);   //  10 MiB  mesh-term precompute
  u16*  He    = (u16*)(ws + 112 * MiB);  // 128 MiB  He / Hn / Hg
  u8*   Big   =  ws + 240 * MiB;         // 128 MiB  Ebf (persists thru k_agg) -> N2 -> G2
  u16*  Ebf   = (u16*)Big;
  float* N2   = (float*)Big;
  u16*  G2    = (u16*)Big;

  float* grid_out = (float*)d_out;
  float* mesh_out = (float*)d_out + (size_t)N_GRID * H;
  // E2 scratch in d_out's grid_out region (exact fit; consumed by k_agg before
  // ln_out_bb writes grid_out)
  u16*  E2    = (u16*)d_out;

  // 1) dst-sort + fused index maps
  k_zero_i32<<<(20992 + 255) / 256, 256, 0, stream>>>(cnt_d, 20992);   // cnt_d + cur_d
  k_hist<<<N_EDGE / 256, 256, 0, stream>>>(dst, cnt_d, N_EDGE);
  k_scan<<<1, 1024, 0, stream>>>(cnt_d, offs_d, N_MESH);
  k_scatter_pos<<<N_EDGE / 256, 256, 0, stream>>>(dst, src, offs_d, cur_d, pos_d, srcD, dstD, N_EDGE);

  // 2) conversions + merged weight prep
  {
    long ng = (long)N_GRID * H, nm = (long)N_MESH * H;
    long spans = (ng + nm) / 8;
    k_conv2<<<(int)((spans + 255) / 256), 256, 0, stream>>>(grid_f, Gbf, ng, mesh_f, Mbf, nm);
  }
  k_conv_perm<<<N_EDGE / 4, 256, 0, stream>>>(edge_f, pos_d, Ebf, N_EDGE);
  {
    const int total = 512 * 1024 * 2 + 512 * 512 * 5;   // 2,359,296
    k_prep_w<<<(total + 255) / 256, 256, 0, stream>>>(We1, We2, Wn1, Wn2, Wg1, Wg2,
                                                      We1t, Wpm, We2t, Wn1t, Wn2t, Wg1t, Wg2t);
  }

  // 3) mesh-term precompute: Pm = Mbf * We1[1024:1536]
  dim3 gpm((N_MESH + 127) / 128, 4);
  k_gemm<0, 1><<<gpm, 256, 0, stream>>>(Mbf, nullptr, nullptr, nullptr, nullptr, Wpm, nullptr, Pm, N_MESH, 512);

  // 4) edge MLP in dst-sorted row order; E2 -> d_out scratch
  dim3 ge1(2, N_EDGE / 256);
  k_gemm256<1, 3><<<ge1, 512, 0, stream>>>(Ebf, Gbf, Pm, srcD, dstD, We1t, be1, He, N_EDGE, 1024);
  k_gemm256<0, 1><<<ge1, 512, 0, stream>>>(He, nullptr, nullptr, nullptr, nullptr, We2t, nullptr, E2, N_EDGE, 512);
  k_agg<<<(N_MESH + 3) / 4, 256, 0, stream>>>(E2, be2, ge, bbe, Ebf, offs_d, AggBf, N_MESH);

  // 5) node MLP
  dim3 gn1((N_MESH + 127) / 128, 4);
  k_gemm<1, 0><<<gn1, 256, 0, stream>>>(Mbf, AggBf, nullptr, nullptr, nullptr, Wn1t, bn1, He, N_MESH, 1024);
  k_gemm<0, 2><<<gn1, 256, 0, stream>>>(He, nullptr, nullptr, nullptr, nullptr, Wn2t, nullptr, N2, N_MESH, 512);
  k_ln_out<<<(N_MESH + 3) / 4, 256, 0, stream>>>(N2, bn2, gn, bbn, mesh_f, mesh_out, N_MESH);

  // 6) grid MLP (G2 bf16 in Big; grid_out written last)
  dim3 gg1(2, N_GRID / 256);
  k_gemm256<0, 0><<<gg1, 512, 0, stream>>>(Gbf, nullptr, nullptr, nullptr, nullptr, Wg1t, bg1, He, N_GRID, 512);
  k_gemm256<0, 1><<<gg1, 512, 0, stream>>>(He, nullptr, nullptr, nullptr, nullptr, Wg2t, nullptr, G2, N_GRID, 512);
  k_ln_out_bb<<<N_GRID / 4, 256, 0, stream>>>(G2, bg2, gg, bbg, Gbf, grid_out, N_GRID);
}